// Round 4
// baseline (15579.201 us; speedup 1.0000x reference)
//
#include <hip/hip_runtime.h>
#include <hip/hip_cooperative_groups.h>
#include <cstdint>
#include <cstddef>

namespace cg = cooperative_groups;

#define T_ 64
#define S_ 400
#define B_ 32
#define H_ 512
#define E_ 1024
#define I_ 128

__device__ __forceinline__ float sigmoid_(float x){ return 1.0f/(1.0f + __expf(-x)); }
__device__ __forceinline__ float tanh_(float x){
    float e = __expf(2.0f*fabsf(x));
    float t = 1.0f - 2.0f/(e + 1.0f);
    return copysignf(t, x);
}
__device__ __forceinline__ void fma4_(float& acc, float4 a, float4 b){
    acc = fmaf(a.x,b.x,acc); acc = fmaf(a.y,b.y,acc);
    acc = fmaf(a.z,b.z,acc); acc = fmaf(a.w,b.w,acc);
}

// ---------------- one-time kernels ----------------

__global__ __launch_bounds__(256) void init_kernel(const float* __restrict__ init_state,
        const float* __restrict__ init_cov, float* __restrict__ h_g, float* __restrict__ covg){
    int i = blockIdx.x*256 + threadIdx.x;
    if (i < B_*H_) h_g[i] = init_state[i];
    if (i < B_*S_) covg[i] = init_cov[i];
}

// harness reads whole d_out as float32 — emit index VALUES as floats.
__global__ __launch_bounds__(256) void xidx_kernel(const int* __restrict__ x_index, float* __restrict__ out){
    int i = blockIdx.x*256 + threadIdx.x;
    if (i >= T_*B_*S_) return;
    int s = i % S_;
    int b = (i / S_) % B_;
    out[i] = (float)x_index[s*B_ + b];
}

// Wh_enc[m, f] = sum_k enc[m, k] * W_h[f, k];  m = s*B+b  (M=12800, N=1024, K=1024)
#define BM 64
#define BN 64
#define BK 16
__global__ __launch_bounds__(256) void gemm_whenc(const float* __restrict__ A,
        const float* __restrict__ Bw, float* __restrict__ C){
    __shared__ float As[BK][BM];
    __shared__ float Bs[BK][BN];
    int bm = blockIdx.x;      // 200
    int bn = blockIdx.y;      // 16
    int tid = threadIdx.x;
    int lrow  = tid >> 2;        // 0..63
    int lcol4 = (tid & 3) * 4;   // 0,4,8,12
    int tx = tid & 15, ty = tid >> 4;
    const float* Ab = A  + (size_t)(bm*BM)*1024;
    const float* Bb = Bw + (size_t)(bn*BN)*1024;
    float acc[4][4] = {};
    for (int k0 = 0; k0 < 1024; k0 += BK){
        float4 av = *(const float4*)(Ab + (size_t)lrow*1024 + k0 + lcol4);
        float4 bv = *(const float4*)(Bb + (size_t)lrow*1024 + k0 + lcol4);
        As[lcol4+0][lrow]=av.x; As[lcol4+1][lrow]=av.y; As[lcol4+2][lrow]=av.z; As[lcol4+3][lrow]=av.w;
        Bs[lcol4+0][lrow]=bv.x; Bs[lcol4+1][lrow]=bv.y; Bs[lcol4+2][lrow]=bv.z; Bs[lcol4+3][lrow]=bv.w;
        __syncthreads();
        #pragma unroll
        for (int kk = 0; kk < BK; ++kk){
            float4 a4 = *(const float4*)&As[kk][ty*4];
            float4 b4 = *(const float4*)&Bs[kk][tx*4];
            float a_[4] = {a4.x, a4.y, a4.z, a4.w};
            float b_[4] = {b4.x, b4.y, b4.z, b4.w};
            #pragma unroll
            for (int i=0;i<4;++i)
                #pragma unroll
                for (int j=0;j<4;++j) acc[i][j] = fmaf(a_[i], b_[j], acc[i][j]);
        }
        __syncthreads();
    }
    int m0 = bm*BM + ty*4, n0 = bn*BN + tx*4;
    #pragma unroll
    for (int i=0;i<4;++i){
        float4 o = make_float4(acc[i][0], acc[i][1], acc[i][2], acc[i][3]);
        *(float4*)&C[(size_t)(m0+i)*E_ + n0] = o;
    }
}

// ---------------- persistent decoder ----------------

struct PArgs {
    const float *y, *enc, *xmask, *ymask, *whenc;
    const float *w_ih1, *w_hh1, *b_ih1, *b_hh1;
    const float *w_ih2, *w_hh2, *b_ih2, *b_hh2;
    const float *W_s, *b_attn, *W_c, *V;
    float *s1g, *qbg, *h_g, *covg, *scoresg;
    float *out_hidden, *out_ctx, *out_wa, *out_cov;
};

// GRU phase: block owns h = {2*bid, 2*bid+1} for all 32 b.
// thread = (b = tid>>3, seg = tid&7). 12 partial dots, butterfly over seg bits.
// WIH_LDS: x-weights from LDS (packed [6][XDIM]) or from global rows.
template<int XDIM, bool WIH_LDS>
__device__ __forceinline__ void gru_phase(int bid, int tid, int t,
        const float* __restrict__ xsrc,          // [B][XDIM]
        const float* __restrict__ hsrc,          // [B][H]
        const float* __restrict__ wih,           // LDS [6][XDIM] or global (3H, XDIM)
        const float* __restrict__ whh_l,         // LDS [6][H]
        const float* __restrict__ b_ih, const float* __restrict__ b_hh,
        const float* __restrict__ ymask,
        float* __restrict__ dest, float* __restrict__ dest2)
{
    constexpr int XSEG = XDIM/8;
    int b = tid >> 3, seg = tid & 7;
    const float* xb = xsrc + (size_t)b*XDIM + seg*XSEG;
    const float* hb = hsrc + (size_t)b*H_ + seg*64;
    float acc[12];
    #pragma unroll
    for (int j=0;j<12;++j) acc[j]=0.f;
    #pragma unroll
    for (int g=0; g<3; ++g){
        const float* wr0;
        const float* wr1;
        if (WIH_LDS){
            wr0 = wih + (g*2+0)*XDIM + seg*XSEG;
            wr1 = wih + (g*2+1)*XDIM + seg*XSEG;
        } else {
            wr0 = wih + (size_t)(g*H_ + 2*bid + 0)*XDIM + seg*XSEG;
            wr1 = wih + (size_t)(g*H_ + 2*bid + 1)*XDIM + seg*XSEG;
        }
        #pragma unroll 4
        for (int k=0; k<XSEG; k+=4){
            float4 xv = *(const float4*)(xb + k);
            fma4_(acc[g*2+0], xv, *(const float4*)(wr0 + k));
            fma4_(acc[g*2+1], xv, *(const float4*)(wr1 + k));
        }
        const float* hr0 = whh_l + (g*2+0)*H_ + seg*64;
        const float* hr1 = whh_l + (g*2+1)*H_ + seg*64;
        #pragma unroll 4
        for (int k=0; k<64; k+=4){
            float4 hv = *(const float4*)(hb + k);
            fma4_(acc[6+g*2+0], hv, *(const float4*)(hr0 + k));
            fma4_(acc[6+g*2+1], hv, *(const float4*)(hr1 + k));
        }
    }
    #pragma unroll
    for (int j=0;j<12;++j){
        acc[j] += __shfl_xor(acc[j], 1);
        acc[j] += __shfl_xor(acc[j], 2);
        acc[j] += __shfl_xor(acc[j], 4);
    }
    if (seg == 0){
        float ym = ymask[t*B_ + b];
        #pragma unroll
        for (int hh=0; hh<2; ++hh){
            int h = 2*bid + hh;
            float gi_r = acc[0+hh] + b_ih[0*H_ + h];
            float gi_z = acc[2+hh] + b_ih[1*H_ + h];
            float gi_n = acc[4+hh] + b_ih[2*H_ + h];
            float gh_r = acc[6+0+hh] + b_hh[0*H_ + h];
            float gh_z = acc[6+2+hh] + b_hh[1*H_ + h];
            float gh_n = acc[6+4+hh] + b_hh[2*H_ + h];
            float r = sigmoid_(gi_r + gh_r);
            float z = sigmoid_(gi_z + gh_z);
            float n = tanh_(gi_n + r*gh_n);
            float hv = hsrc[(size_t)b*H_ + h];
            float o = ym*((1.f - z)*n + z*hv) + (1.f - ym)*hv;
            dest[(size_t)b*H_ + h] = o;
            if (dest2) dest2[(size_t)b*H_ + h] = o;
        }
    }
}

__global__ __launch_bounds__(256, 1) void decoder_persistent(PArgs a){
    cg::grid_group grid = cg::this_grid();
    extern __shared__ float smem[];
    float* wih1_l = smem;                  // 6*128  = 768
    float* whh1_l = wih1_l + 6*I_;         // 6*512  = 3072
    float* whh2_l = whh1_l + 6*H_;         // 6*512  = 3072
    float* wsr    = whh2_l + 6*H_;         // 4*512  = 2048
    float* wc_l   = wsr + 4*H_;            // 1024
    float* v_l    = wc_l + E_;             // 1024
    float* ps     = v_l + E_;              // 400
    float* tmp    = ps + S_;               // 128
    float* red    = tmp + 128;             // 16

    const int tid = threadIdx.x;
    const int bid = blockIdx.x;

    // ---- one-time LDS preload of this block's weight slices ----
    for (int i = tid; i < 6*I_; i += 256){
        int j = i >> 7, k = i & (I_-1);
        int g = j >> 1, hh = j & 1;
        wih1_l[i] = a.w_ih1[(size_t)(g*H_ + 2*bid + hh)*I_ + k];
    }
    for (int i = tid; i < 6*H_; i += 256){
        int j = i >> 9, k = i & (H_-1);
        int g = j >> 1, hh = j & 1;
        whh1_l[i] = a.w_hh1[(size_t)(g*H_ + 2*bid + hh)*H_ + k];
        whh2_l[i] = a.w_hh2[(size_t)(g*H_ + 2*bid + hh)*H_ + k];
    }
    for (int i = tid; i < 4*H_; i += 256){
        int j = i >> 9, k = i & (H_-1);
        wsr[i] = a.W_s[(size_t)(4*bid + j)*H_ + k];
    }
    for (int i = tid; i < E_; i += 256){
        wc_l[i] = a.W_c[i];
        v_l[i]  = a.V[i];
    }
    __syncthreads();

    for (int t = 0; t < T_; ++t){
        // ---- GRU1 -> s1g ----
        gru_phase<I_, true>(bid, tid, t, a.y + (size_t)t*B_*I_, a.h_g,
                            wih1_l, whh1_l, a.b_ih1, a.b_hh1, a.ymask, a.s1g, nullptr);
        grid.sync();

        // ---- QPROJ -> qbg (block owns f = 4*bid .. +3) ----
        {
            int b = tid >> 3, seg = tid & 7;
            const float* sb = a.s1g + (size_t)b*H_ + seg*64;
            float acc[4] = {0.f,0.f,0.f,0.f};
            #pragma unroll 4
            for (int k=0;k<64;k+=4){
                float4 sv = *(const float4*)(sb + k);
                #pragma unroll
                for (int j=0;j<4;++j)
                    fma4_(acc[j], sv, *(const float4*)(wsr + j*H_ + seg*64 + k));
            }
            #pragma unroll
            for (int j=0;j<4;++j){
                acc[j] += __shfl_xor(acc[j],1);
                acc[j] += __shfl_xor(acc[j],2);
                acc[j] += __shfl_xor(acc[j],4);
            }
            if (seg == 0){
                #pragma unroll
                for (int j=0;j<4;++j){
                    int f = 4*bid + j;
                    a.qbg[(size_t)b*E_ + f] = acc[j] + a.b_attn[f];
                }
            }
        }
        grid.sync();

        // ---- SCORE: block handles 50 flat (s*32+b) pairs, wave-per-pair ----
        {
            int wid = tid >> 6, lane = tid & 63;
            int base = bid*50;
            #pragma unroll 1
            for (int i = 0; i < 13; ++i){
                int pi = base + wid + 4*i;
                if (pi >= base + 50) break;
                int s = pi >> 5, b = pi & 31;
                const float* wp = a.whenc + (size_t)pi*E_;   // row m = s*B+b == pi
                const float* qp = a.qbg + (size_t)b*E_;
                float cv = a.covg[b*S_ + s];
                float acc = 0.f;
                #pragma unroll
                for (int pass=0; pass<4; ++pass){
                    int e = pass*256 + lane*4;
                    float4 w4 = *(const float4*)(wp + e);
                    float4 q4 = *(const float4*)(qp + e);
                    float4 c4 = *(const float4*)(wc_l + e);
                    float4 v4 = *(const float4*)(v_l + e);
                    acc = fmaf(v4.x, tanh_(w4.x + q4.x + cv*c4.x), acc);
                    acc = fmaf(v4.y, tanh_(w4.y + q4.y + cv*c4.y), acc);
                    acc = fmaf(v4.z, tanh_(w4.z + q4.z + cv*c4.z), acc);
                    acc = fmaf(v4.w, tanh_(w4.w + q4.w + cv*c4.w), acc);
                }
                #pragma unroll
                for (int off=32; off; off>>=1) acc += __shfl_xor(acc, off);
                if (lane == 0){
                    float xm = a.xmask[s*B_ + b];
                    a.scoresg[b*S_ + s] = (xm == 0.f) ? -1e9f : acc*xm;
                }
            }
        }
        grid.sync();

        // ---- CTX (+softmax, wa/cov): block = (b = bid>>3, e-slice = (bid&7)*128) ----
        {
            int b = bid >> 3, e0 = (bid & 7)*128;
            float v0g = a.scoresg[b*S_ + tid];
            float v1g = (tid+256 < S_) ? a.scoresg[b*S_ + tid + 256] : -1e30f;
            float mx = fmaxf(v0g, v1g);
            #pragma unroll
            for (int off=32; off; off>>=1) mx = fmaxf(mx, __shfl_xor(mx, off));
            int wid = tid >> 6, lane = tid & 63;
            if (lane == 0) red[wid] = mx;
            __syncthreads();
            mx = fmaxf(fmaxf(red[0],red[1]), fmaxf(red[2],red[3]));
            float e0v = __expf(v0g - mx);
            float e1v = (tid+256 < S_) ? __expf(v1g - mx) : 0.f;
            float sm = e0v + e1v;
            #pragma unroll
            for (int off=32; off; off>>=1) sm += __shfl_xor(sm, off);
            if (lane == 0) red[8+wid] = sm;
            __syncthreads();
            float rden = 1.f/(red[8]+red[9]+red[10]+red[11]);
            ps[tid] = e0v*rden;
            if (tid+256 < S_) ps[tid+256] = e1v*rden;
            __syncthreads();
            // ctx reduce: thread = (sh = tid>>7 in {0,1}, eo = tid&127)
            int sh = tid >> 7, eo = tid & 127;
            const float* ep = a.enc + (size_t)b*E_ + e0 + eo;
            float acc = 0.f;
            int sbeg = sh*200;
            #pragma unroll 4
            for (int s = sbeg; s < sbeg+200; ++s)
                acc = fmaf(ps[s], ep[(size_t)s*(B_*E_)], acc);
            if (sh == 1) tmp[eo] = acc;
            __syncthreads();
            if (sh == 0){
                float cv = acc + tmp[eo];
                a.out_ctx[(size_t)t*B_*E_ + (size_t)b*E_ + e0 + eo] = cv;
            }
            if ((bid & 7) == 0){
                for (int s = tid; s < S_; s += 256){
                    float c = a.covg[b*S_ + s];
                    a.out_wa [(size_t)t*B_*S_ + (size_t)b*S_ + s] = ps[s];
                    a.out_cov[(size_t)t*B_*S_ + (size_t)b*S_ + s] = c;
                    a.covg[b*S_ + s] = c + ps[s];
                }
            }
        }
        grid.sync();

        // ---- GRU2 -> h_g (+out_hidden); x = ctx (from out_ctx), h-input = s1 ----
        gru_phase<E_, false>(bid, tid, t, a.out_ctx + (size_t)t*B_*E_, a.s1g,
                             a.w_ih2, whh2_l, a.b_ih2, a.b_hh2, a.ymask, a.h_g,
                             a.out_hidden + (size_t)t*B_*H_);
        grid.sync();
    }
}

// ---------------- launch ----------------

extern "C" void kernel_launch(void* const* d_in, const int* in_sizes, int n_in,
                              void* d_out, int out_size, void* d_ws, size_t ws_size,
                              hipStream_t stream) {
    const float* y          = (const float*)d_in[0];
    const float* enc        = (const float*)d_in[1];
    const float* init_state = (const float*)d_in[2];
    const float* xmask      = (const float*)d_in[3];
    const float* ymask      = (const float*)d_in[4];
    const int*   x_index    = (const int*)  d_in[5];
    const float* init_cov   = (const float*)d_in[6];
    const float* W_h        = (const float*)d_in[7];
    const float* W_s        = (const float*)d_in[8];
    const float* W_c        = (const float*)d_in[9];
    const float* b_attn     = (const float*)d_in[10];
    const float* Vv         = (const float*)d_in[11];
    const float* w_ih1      = (const float*)d_in[12];
    const float* w_hh1      = (const float*)d_in[13];
    const float* b_ih1      = (const float*)d_in[14];
    const float* b_hh1      = (const float*)d_in[15];
    const float* w_ih2      = (const float*)d_in[16];
    const float* w_hh2      = (const float*)d_in[17];
    const float* b_ih2      = (const float*)d_in[18];
    const float* b_hh2      = (const float*)d_in[19];

    float* out        = (float*)d_out;
    float* out_hidden = out;                                   // T*B*H
    float* out_ctx    = out_hidden + (size_t)T_*B_*H_;         // T*B*E
    float* out_wa     = out_ctx    + (size_t)T_*B_*E_;         // T*B*S
    float* out_xidx   = out_wa     + (size_t)T_*B_*S_;         // T*B*S (float values)
    float* out_cov    = out_xidx   + (size_t)T_*B_*S_;         // T*B*S

    float* ws      = (float*)d_ws;
    float* whenc   = ws;                             // S*B*E
    float* s1g     = whenc + (size_t)S_*B_*E_;       // B*H
    float* qbg     = s1g   + (size_t)B_*H_;          // B*E
    float* h_g     = qbg   + (size_t)B_*E_;          // B*H
    float* covg    = h_g   + (size_t)B_*H_;          // B*S
    float* scoresg = covg  + (size_t)B_*S_;          // B*S

    init_kernel<<<64, 256, 0, stream>>>(init_state, init_cov, h_g, covg);
    xidx_kernel<<<3200, 256, 0, stream>>>(x_index, out_xidx);
    gemm_whenc<<<dim3(200, 16), 256, 0, stream>>>(enc, W_h, whenc);

    PArgs pa;
    pa.y = y; pa.enc = enc; pa.xmask = xmask; pa.ymask = ymask; pa.whenc = whenc;
    pa.w_ih1 = w_ih1; pa.w_hh1 = w_hh1; pa.b_ih1 = b_ih1; pa.b_hh1 = b_hh1;
    pa.w_ih2 = w_ih2; pa.w_hh2 = w_hh2; pa.b_ih2 = b_ih2; pa.b_hh2 = b_hh2;
    pa.W_s = W_s; pa.b_attn = b_attn; pa.W_c = W_c; pa.V = Vv;
    pa.s1g = s1g; pa.qbg = qbg; pa.h_g = h_g; pa.covg = covg; pa.scoresg = scoresg;
    pa.out_hidden = out_hidden; pa.out_ctx = out_ctx; pa.out_wa = out_wa; pa.out_cov = out_cov;

    void* args[] = { &pa };
    // LDS: (768+3072+3072+2048+1024+1024+400+128+16)*4 = 46208 B
    hipLaunchCooperativeKernel((const void*)decoder_persistent, dim3(256), dim3(256),
                               args, 46208, stream);
}

// Round 5
// 7527.921 us; speedup vs baseline: 2.0695x; 2.0695x over previous
//
#include <hip/hip_runtime.h>
#include <hip/hip_cooperative_groups.h>
#include <cstdint>
#include <cstddef>

#define T_ 64
#define S_ 400
#define B_ 32
#define H_ 512
#define E_ 1024
#define I_ 128
#define NBLK 256
#define NTHR 1024

__device__ __forceinline__ float sigmoid_(float x){ return 1.0f/(1.0f + __expf(-x)); }
__device__ __forceinline__ float tanh_(float x){
    float e = __expf(2.0f*fabsf(x));
    float t = 1.0f - 2.0f/(e + 1.0f);
    return copysignf(t, x);
}
__device__ __forceinline__ void fma4_(float& acc, float4 a, float4 b){
    acc = fmaf(a.x,b.x,acc); acc = fmaf(a.y,b.y,acc);
    acc = fmaf(a.z,b.z,acc); acc = fmaf(a.w,b.w,acc);
}
__device__ __forceinline__ float4 ld4(const float* p){ return *(const float4*)p; }
// agent-scope (device-coherent, L2-bypass) store: cross-block visible after vmcnt drain
__device__ __forceinline__ void ast(float* p, float v){
    __hip_atomic_store(p, v, __ATOMIC_RELAXED, __HIP_MEMORY_SCOPE_AGENT);
}

// ---------------- one-time kernels ----------------

// zero barrier pool; out_cov row 0 = init coverage
__global__ __launch_bounds__(256) void init_kernel(const float* __restrict__ init_cov,
        float* __restrict__ out_cov0, unsigned* __restrict__ bar){
    int i = blockIdx.x*256 + threadIdx.x;
    if (i < B_*S_) out_cov0[i] = init_cov[i];
    for (int j = i; j < 320*288; j += gridDim.x*256) bar[j] = 0u;
}

// harness reads whole d_out as float32 — emit index VALUES as floats.
__global__ __launch_bounds__(256) void xidx_kernel(const int* __restrict__ x_index, float* __restrict__ out){
    int i = blockIdx.x*256 + threadIdx.x;
    if (i >= T_*B_*S_) return;
    int s = i % S_;
    int b = (i / S_) % B_;
    out[i] = (float)x_index[s*B_ + b];
}

// Wh_enc[m, f] = sum_k enc[m, k] * W_h[f, k];  m = s*B+b  (M=12800, N=1024, K=1024)
#define BM 64
#define BN 64
#define BK 16
__global__ __launch_bounds__(256) void gemm_whenc(const float* __restrict__ A,
        const float* __restrict__ Bw, float* __restrict__ C){
    __shared__ float As[BK][BM];
    __shared__ float Bs[BK][BN];
    int bm = blockIdx.x;
    int bn = blockIdx.y;
    int tid = threadIdx.x;
    int lrow  = tid >> 2;
    int lcol4 = (tid & 3) * 4;
    int tx = tid & 15, ty = tid >> 4;
    const float* Ab = A  + (size_t)(bm*BM)*1024;
    const float* Bb = Bw + (size_t)(bn*BN)*1024;
    float acc[4][4] = {};
    for (int k0 = 0; k0 < 1024; k0 += BK){
        float4 av = *(const float4*)(Ab + (size_t)lrow*1024 + k0 + lcol4);
        float4 bv = *(const float4*)(Bb + (size_t)lrow*1024 + k0 + lcol4);
        As[lcol4+0][lrow]=av.x; As[lcol4+1][lrow]=av.y; As[lcol4+2][lrow]=av.z; As[lcol4+3][lrow]=av.w;
        Bs[lcol4+0][lrow]=bv.x; Bs[lcol4+1][lrow]=bv.y; Bs[lcol4+2][lrow]=bv.z; Bs[lcol4+3][lrow]=bv.w;
        __syncthreads();
        #pragma unroll
        for (int kk = 0; kk < BK; ++kk){
            float4 a4 = *(const float4*)&As[kk][ty*4];
            float4 b4 = *(const float4*)&Bs[kk][tx*4];
            float a_[4] = {a4.x, a4.y, a4.z, a4.w};
            float b_[4] = {b4.x, b4.y, b4.z, b4.w};
            #pragma unroll
            for (int i=0;i<4;++i)
                #pragma unroll
                for (int j=0;j<4;++j) acc[i][j] = fmaf(a_[i], b_[j], acc[i][j]);
        }
        __syncthreads();
    }
    int m0 = bm*BM + ty*4, n0 = bn*BN + tx*4;
    #pragma unroll
    for (int i=0;i<4;++i){
        float4 o = make_float4(acc[i][0], acc[i][1], acc[i][2], acc[i][3]);
        *(float4*)&C[(size_t)(m0+i)*E_ + n0] = o;
    }
}

// ---------------- persistent decoder ----------------

struct PArgs {
    const float *y, *enc, *xmask, *ymask, *whenc, *init_state;
    const float *w_ih1, *w_hh1, *b_ih1, *b_hh1;
    const float *w_ih2, *w_hh2, *b_ih2, *b_hh2;
    const float *W_s, *b_attn, *W_c, *V;
    float *s1g, *qbg, *scoresg;
    unsigned *bar;
    float *out_hidden, *out_ctx, *out_wa, *out_cov;
};

// 2-level grid barrier: 16 leaves x 16 blocks, write-once slots (no reset).
// Layout per idx (stride 288 u32): leaves at l*16, root at 256, flag at 272.
__device__ __forceinline__ void gbar(unsigned* barp, int idx, int bid, int tid){
    __syncthreads();
    if (tid == 0){
        unsigned* base = barp + (size_t)idx*288;
        __builtin_amdgcn_fence(__ATOMIC_RELEASE, "agent");
        unsigned o = __hip_atomic_fetch_add(base + (bid & 15)*16, 1u,
                        __ATOMIC_RELAXED, __HIP_MEMORY_SCOPE_AGENT);
        if (o == 15u){
            unsigned r = __hip_atomic_fetch_add(base + 256, 1u,
                            __ATOMIC_RELAXED, __HIP_MEMORY_SCOPE_AGENT);
            if (r == 15u)
                __hip_atomic_store(base + 272, 1u, __ATOMIC_RELAXED, __HIP_MEMORY_SCOPE_AGENT);
        }
        while (__hip_atomic_load(base + 272, __ATOMIC_RELAXED, __HIP_MEMORY_SCOPE_AGENT) == 0u)
            __builtin_amdgcn_s_sleep(2);
        __builtin_amdgcn_fence(__ATOMIC_ACQUIRE, "agent");
    }
    __syncthreads();
}

// GRU phase: block owns h-pair {2bid, 2bid+1} for all 32 b.
// thread = (b = tid>>5, seg = tid&31). 12 partial dots, butterfly over 5 seg bits.
// LDS weights chunk-major: float4 slot (j*32+seg) of row r holds cols seg*(D/32)+j*4.
template<int XDIM, bool XLDS>
__device__ __forceinline__ void gru_phase2(int bid, int tid, int t,
        const float* __restrict__ xsrc, const float* __restrict__ hsrc,
        const float* __restrict__ wih, const float* __restrict__ whh_l,
        const float* __restrict__ b_ih, const float* __restrict__ b_hh,
        const float* __restrict__ ymask, float* __restrict__ dest)
{
    constexpr int XC = XDIM/128;                 // float4 chunks per thread
    int b = tid >> 5, seg = tid & 31;
    float4 xv[XC], hv[4];
    const float* xb = xsrc + (size_t)b*XDIM + seg*(XDIM/32);
    #pragma unroll
    for (int j=0;j<XC;++j) xv[j] = ld4(xb + j*4);
    const float* hb = hsrc + (size_t)b*H_ + seg*16;
    #pragma unroll
    for (int j=0;j<4;++j) hv[j] = ld4(hb + j*4);
    float acc[12];
    #pragma unroll
    for (int r=0;r<12;++r) acc[r] = 0.f;
    #pragma unroll
    for (int r=0;r<6;++r){
        if (XLDS){
            #pragma unroll
            for (int j=0;j<XC;++j)
                fma4_(acc[r], xv[j], *(const float4*)(wih + r*XDIM + (j*32+seg)*4));
        } else {
            const float* wr = wih + (size_t)((r>>1)*H_ + 2*bid + (r&1))*XDIM + seg*(XDIM/32);
            #pragma unroll
            for (int j=0;j<XC;++j) fma4_(acc[r], xv[j], ld4(wr + j*4));
        }
        #pragma unroll
        for (int j=0;j<4;++j)
            fma4_(acc[6+r], hv[j], *(const float4*)(whh_l + r*H_ + (j*32+seg)*4));
    }
    #pragma unroll
    for (int r=0;r<12;++r){
        acc[r] += __shfl_xor(acc[r], 1);
        acc[r] += __shfl_xor(acc[r], 2);
        acc[r] += __shfl_xor(acc[r], 4);
        acc[r] += __shfl_xor(acc[r], 8);
        acc[r] += __shfl_xor(acc[r], 16);
    }
    if (seg == 0){
        float ym = ymask[t*B_ + b];
        #pragma unroll
        for (int hh=0; hh<2; ++hh){
            int h = 2*bid + hh;
            float rr = sigmoid_(acc[0+hh] + b_ih[h]       + acc[6+hh]  + b_hh[h]);
            float zz = sigmoid_(acc[2+hh] + b_ih[H_+h]    + acc[8+hh]  + b_hh[H_+h]);
            float nn = tanh_(acc[4+hh] + b_ih[2*H_+h] + rr*(acc[10+hh] + b_hh[2*H_+h]));
            float hvv = hsrc[(size_t)b*H_ + h];
            float o = ym*((1.f - zz)*nn + zz*hvv) + (1.f - ym)*hvv;
            ast(dest + (size_t)b*H_ + h, o);
        }
    }
}

__global__ __launch_bounds__(NTHR, 4) void decoder_persistent(PArgs a){
    __shared__ float wih1_l[6*I_];
    __shared__ float whh1_l[6*H_];
    __shared__ float whh2_l[6*H_];
    __shared__ float wsr_l[4*H_];
    __shared__ float wc_l[E_];
    __shared__ float v_l[E_];
    __shared__ float ps[S_];
    __shared__ float tmp[8*128];
    __shared__ float red[32];

    const int tid = threadIdx.x;
    const int bid = blockIdx.x;

    // ---- one-time LDS preload (chunk-major for conflict-free ds_read_b128) ----
    // wih1: D=128, XC=1 -> identity row copy
    for (int p = tid; p < 6*I_; p += NTHR){
        int r = p >> 7, c = p & 127;
        wih1_l[p] = a.w_ih1[(size_t)((r>>1)*H_ + 2*bid + (r&1))*I_ + c];
    }
    // whh1/whh2: D=512, slot = j*32+seg holds cols seg*16 + j*4
    for (int p = tid; p < 6*128; p += NTHR){
        int r = p >> 7, slot = p & 127;
        int j = slot >> 5, seg = slot & 31;
        size_t row = (size_t)((r>>1)*H_ + 2*bid + (r&1));
        float4 v1 = ld4(a.w_hh1 + row*H_ + seg*16 + j*4);
        float4 v2 = ld4(a.w_hh2 + row*H_ + seg*16 + j*4);
        *(float4*)(whh1_l + r*H_ + slot*4) = v1;
        *(float4*)(whh2_l + r*H_ + slot*4) = v2;
    }
    // W_s rows 4bid..4bid+3, chunk-major
    for (int p = tid; p < 4*128; p += NTHR){
        int r = p >> 7, slot = p & 127;
        int j = slot >> 5, seg = slot & 31;
        float4 v1 = ld4(a.W_s + (size_t)(4*bid + r)*H_ + seg*16 + j*4);
        *(float4*)(wsr_l + r*H_ + slot*4) = v1;
    }
    for (int i = tid; i < E_; i += NTHR){
        wc_l[i] = a.W_c[i];
        v_l[i]  = a.V[i];
    }
    __syncthreads();

    for (int t = 0; t < T_; ++t){
        const float* hprev = t ? (a.out_hidden + (size_t)(t-1)*B_*H_) : a.init_state;
        float* s1t  = a.s1g     + (size_t)t*B_*H_;
        float* qbt  = a.qbg     + (size_t)t*B_*E_;
        float* sct  = a.scoresg + (size_t)t*B_*S_;
        const float* covr = a.out_cov + (size_t)t*B_*S_;

        // ---- GRU1 -> s1t ----
        gru_phase2<I_, true>(bid, tid, t, a.y + (size_t)t*B_*I_, hprev,
                             wih1_l, whh1_l, a.b_ih1, a.b_hh1, a.ymask, s1t);
        gbar(a.bar, t*5+0, bid, tid);

        // ---- QPROJ -> qbt (block owns f = 4bid..4bid+3) ----
        {
            int b = tid >> 5, seg = tid & 31;
            const float* sb = s1t + (size_t)b*H_ + seg*16;
            float4 sv[4];
            #pragma unroll
            for (int j=0;j<4;++j) sv[j] = ld4(sb + j*4);
            float acc[4] = {0.f,0.f,0.f,0.f};
            #pragma unroll
            for (int jf=0;jf<4;++jf)
                #pragma unroll
                for (int jj=0;jj<4;++jj)
                    fma4_(acc[jf], sv[jj], *(const float4*)(wsr_l + jf*H_ + (jj*32+seg)*4));
            #pragma unroll
            for (int jf=0;jf<4;++jf){
                acc[jf] += __shfl_xor(acc[jf], 1);
                acc[jf] += __shfl_xor(acc[jf], 2);
                acc[jf] += __shfl_xor(acc[jf], 4);
                acc[jf] += __shfl_xor(acc[jf], 8);
                acc[jf] += __shfl_xor(acc[jf], 16);
            }
            if (seg == 0){
                #pragma unroll
                for (int jf=0;jf<4;++jf){
                    int f = 4*bid + jf;
                    ast(qbt + (size_t)b*E_ + f, acc[jf] + a.b_attn[f]);
                }
            }
        }
        gbar(a.bar, t*5+1, bid, tid);

        // ---- SCORE: 50 flat rows (m = s*32+b) per block, one wave per row ----
        {
            int wid = tid >> 6, lane = tid & 63;
            #pragma unroll 1
            for (int k = 0; k < 4; ++k){
                int ri = wid + (k << 4);
                if (ri >= 50) break;
                int pi = bid*50 + ri;
                int s = pi >> 5, b = pi & 31;
                const float* wp = a.whenc + (size_t)pi*E_;
                const float* qp = qbt + (size_t)b*E_;
                float cv = covr[b*S_ + s];
                float acc = 0.f;
                #pragma unroll
                for (int pass=0; pass<4; ++pass){
                    int e = pass*256 + lane*4;
                    float4 w4 = ld4(wp + e);
                    float4 q4 = ld4(qp + e);
                    float4 c4 = *(const float4*)(wc_l + e);
                    float4 v4 = *(const float4*)(v_l + e);
                    acc = fmaf(v4.x, tanh_(w4.x + q4.x + cv*c4.x), acc);
                    acc = fmaf(v4.y, tanh_(w4.y + q4.y + cv*c4.y), acc);
                    acc = fmaf(v4.z, tanh_(w4.z + q4.z + cv*c4.z), acc);
                    acc = fmaf(v4.w, tanh_(w4.w + q4.w + cv*c4.w), acc);
                }
                #pragma unroll
                for (int off=32; off; off>>=1) acc += __shfl_xor(acc, off);
                if (lane == 0){
                    float xm = a.xmask[s*B_ + b];
                    ast(sct + (size_t)b*S_ + s, (xm == 0.f) ? -1e9f : acc*xm);
                }
            }
        }
        gbar(a.bar, t*5+2, bid, tid);

        // ---- CTX: block = (b = bid>>3, e-slice = (bid&7)*128), softmax block-redundant ----
        {
            int b = bid >> 3, e0 = (bid & 7) << 7;
            int wid = tid >> 6, lane = tid & 63;
            const float* srow = sct + (size_t)b*S_;
            float v = (tid < S_) ? srow[tid] : -1e30f;
            float mx = v;
            #pragma unroll
            for (int off=32; off; off>>=1) mx = fmaxf(mx, __shfl_xor(mx, off));
            if (lane == 0) red[wid] = mx;
            __syncthreads();
            float m = red[0];
            #pragma unroll
            for (int i=1;i<16;++i) m = fmaxf(m, red[i]);
            float ev = (tid < S_) ? __expf(v - m) : 0.f;
            float sm = ev;
            #pragma unroll
            for (int off=32; off; off>>=1) sm += __shfl_xor(sm, off);
            if (lane == 0) red[16 + wid] = sm;
            __syncthreads();
            float tot = red[16];
            #pragma unroll
            for (int i=1;i<16;++i) tot += red[16+i];
            float rden = 1.f/tot;
            if (tid < S_) ps[tid] = ev*rden;
            __syncthreads();
            // reduce: thread (sh = tid>>7 in 0..7, eo = tid&127); shard = 50 s each
            int sh = tid >> 7, eo = tid & 127;
            const float* ep = a.enc + (size_t)b*E_ + e0 + eo;
            float acc = 0.f;
            int sbeg = sh*50;
            #pragma unroll 4
            for (int s = sbeg; s < sbeg+50; ++s)
                acc = fmaf(ps[s], ep[(size_t)s*(B_*E_)], acc);
            tmp[sh*128 + eo] = acc;
            __syncthreads();
            if (sh == 0){
                float aa = 0.f;
                #pragma unroll
                for (int i=0;i<8;++i) aa += tmp[i*128 + eo];
                ast(a.out_ctx + (size_t)t*B_*E_ + (size_t)b*E_ + e0 + eo, aa);
            }
            if ((bid & 7) == 0){
                float* covn = a.out_cov + (size_t)(t+1)*B_*S_;
                for (int s2 = tid; s2 < S_; s2 += NTHR){
                    float p = ps[s2];
                    a.out_wa[(size_t)t*B_*S_ + (size_t)b*S_ + s2] = p;   // never re-read
                    if (t < T_-1) ast(covn + (size_t)b*S_ + s2, covr[(size_t)b*S_ + s2] + p);
                }
            }
        }
        gbar(a.bar, t*5+3, bid, tid);

        // ---- GRU2 -> out_hidden[t] (x = ctx, h = s1) ----
        gru_phase2<E_, false>(bid, tid, t, a.out_ctx + (size_t)t*B_*E_, s1t,
                              a.w_ih2, whh2_l, a.b_ih2, a.b_hh2, a.ymask,
                              a.out_hidden + (size_t)t*B_*H_);
        if (t != T_-1) gbar(a.bar, t*5+4, bid, tid);
    }
}

// ---------------- launch ----------------

extern "C" void kernel_launch(void* const* d_in, const int* in_sizes, int n_in,
                              void* d_out, int out_size, void* d_ws, size_t ws_size,
                              hipStream_t stream) {
    const float* y          = (const float*)d_in[0];
    const float* enc        = (const float*)d_in[1];
    const float* init_state = (const float*)d_in[2];
    const float* xmask      = (const float*)d_in[3];
    const float* ymask      = (const float*)d_in[4];
    const int*   x_index    = (const int*)  d_in[5];
    const float* init_cov   = (const float*)d_in[6];
    const float* W_h        = (const float*)d_in[7];
    const float* W_s        = (const float*)d_in[8];
    const float* W_c        = (const float*)d_in[9];
    const float* b_attn     = (const float*)d_in[10];
    const float* Vv         = (const float*)d_in[11];
    const float* w_ih1      = (const float*)d_in[12];
    const float* w_hh1      = (const float*)d_in[13];
    const float* b_ih1      = (const float*)d_in[14];
    const float* b_hh1      = (const float*)d_in[15];
    const float* w_ih2      = (const float*)d_in[16];
    const float* w_hh2      = (const float*)d_in[17];
    const float* b_ih2      = (const float*)d_in[18];
    const float* b_hh2      = (const float*)d_in[19];

    float* out        = (float*)d_out;
    float* out_hidden = out;                                   // T*B*H
    float* out_ctx    = out_hidden + (size_t)T_*B_*H_;         // T*B*E
    float* out_wa     = out_ctx    + (size_t)T_*B_*E_;         // T*B*S
    float* out_xidx   = out_wa     + (size_t)T_*B_*S_;         // T*B*S (float values)
    float* out_cov    = (float*)(out_xidx + (size_t)T_*B_*S_); // T*B*S (also rotating cov state)

    float* ws       = (float*)d_ws;
    float* whenc    = ws;                                   // S*B*E       = 13107200
    float* s1g      = whenc   + (size_t)S_*B_*E_;           // T*B*H       = 1048576
    float* qbg      = s1g     + (size_t)T_*B_*H_;           // T*B*E       = 2097152
    float* scoresg  = qbg     + (size_t)T_*B_*E_;           // T*B*S       = 819200
    unsigned* bar   = (unsigned*)(scoresg + (size_t)T_*B_*S_); // 320*288  = 92160 u32

    init_kernel<<<360, 256, 0, stream>>>(init_cov, out_cov, bar);
    xidx_kernel<<<3200, 256, 0, stream>>>(x_index, out_xidx);
    gemm_whenc<<<dim3(200, 16), 256, 0, stream>>>(enc, W_h, whenc);

    PArgs pa;
    pa.y = y; pa.enc = enc; pa.xmask = xmask; pa.ymask = ymask; pa.whenc = whenc;
    pa.init_state = init_state;
    pa.w_ih1 = w_ih1; pa.w_hh1 = w_hh1; pa.b_ih1 = b_ih1; pa.b_hh1 = b_hh1;
    pa.w_ih2 = w_ih2; pa.w_hh2 = w_hh2; pa.b_ih2 = b_ih2; pa.b_hh2 = b_hh2;
    pa.W_s = W_s; pa.b_attn = b_attn; pa.W_c = W_c; pa.V = Vv;
    pa.s1g = s1g; pa.qbg = qbg; pa.scoresg = scoresg; pa.bar = bar;
    pa.out_hidden = out_hidden; pa.out_ctx = out_ctx; pa.out_wa = out_wa; pa.out_cov = out_cov;

    void* args[] = { &pa };
    hipLaunchCooperativeKernel((const void*)decoder_persistent, dim3(NBLK), dim3(NTHR),
                               args, 0, stream);
}